// Round 3
// baseline (74.409 us; speedup 1.0000x reference)
//
#include <hip/hip_runtime.h>
#include <hip/hip_bf16.h>

#define BB 16
#define SS 512
#define HH 1024

typedef __attribute__((ext_vector_type(4))) float f32x4;
typedef __attribute__((ext_vector_type(8))) short bhalf8;

static __device__ __forceinline__ unsigned int pack2(float a, float b) {
    __hip_bfloat162 h = __float22bfloat162_rn(make_float2(a, b));
    union { __hip_bfloat162 h; unsigned int u; } cv;
    cv.h = h;
    return cv.u;
}

// ---------------------------------------------------------------------------
// Prepass: blocks 0..2047: W[e][k][d] f32 -> Wt[e][d][k] bf16 (only for
// experts actually selected); blocks 2048..2063: zero the row-sum buffer.
// ---------------------------------------------------------------------------
__global__ __launch_bounds__(256)
void prep_kernel(const float* __restrict__ W, const int* __restrict__ eidx,
                 unsigned short* __restrict__ Wt, float* __restrict__ sums)
{
    int bid = blockIdx.x;
    int t = threadIdx.x;
    if (bid < 2048) {
        int e  = bid >> 8;
        bool used = false;
        for (int b = 0; b < BB; ++b) used = used || (eidx[b] == e);
        if (!used) return;
        int rem = bid & 255;
        int kt = rem >> 3, dt = rem & 7;     // 32-k-row x 128-d-col tile
        int kb = t & 7, db = t >> 3;
        const float* src = W + ((size_t)e << 20) + (size_t)(kt * 32 + kb * 4) * HH + dt * 128 + db * 4;
        float4 r0 = *(const float4*)(src);
        float4 r1 = *(const float4*)(src + HH);
        float4 r2 = *(const float4*)(src + 2 * HH);
        float4 r3 = *(const float4*)(src + 3 * HH);
        unsigned short* dst = Wt + ((size_t)e << 20) + (size_t)(dt * 128 + db * 4) * HH + kt * 32 + kb * 4;
#pragma unroll
        for (int c = 0; c < 4; ++c) {
            float c0 = (&r0.x)[c], c1 = (&r1.x)[c], c2 = (&r2.x)[c], c3 = (&r3.x)[c];
            *reinterpret_cast<uint2*>(dst + (size_t)c * HH) =
                make_uint2(pack2(c0, c1), pack2(c2, c3));
        }
    } else {
        int i = (bid - 2048) * 1024 + t * 4;   // 16 blocks cover 16384 floats
        float4 z = {0.f, 0.f, 0.f, 0.f};
        *reinterpret_cast<float4*>(&sums[i]) = z;
    }
}

// ---------------------------------------------------------------------------
// GEMM (+bias+residual) -> writes x to out (f32) + per-row {sum, sumsq} via
// atomics. 512 blocks x 256 thr, 128x128 tile, BK=32, dbuf LDS,
// global_load_lds width-16, mfma 16x16x32 bf16 (16/wave/iter).
// A kept f32 in LDS with XOR slot swizzle (pre-swizzled source + swz read).
// ---------------------------------------------------------------------------
__global__ __launch_bounds__(256, 2)
void moe_gemm_kernel(const float* __restrict__ hid, const float* __restrict__ inp,
                     const int* __restrict__ eidx, const unsigned short* __restrict__ Wt,
                     const float* __restrict__ bias, float* __restrict__ sums,
                     float* __restrict__ out)
{
    __shared__ char lds[49152];   // A: 2x16KB (f32), W: 2x8KB (bf16)

    int bx  = blockIdx.x;
    int swz = (bx & 7) * 64 + (bx >> 3);      // XCD-bijective (512 % 8 == 0)
    int bt   = swz >> 5;
    int tile = swz & 31;
    int mt = tile >> 3, nt = tile & 7;
    int e = eidx[bt];

    int t = threadIdx.x, wave = t >> 6, lane = t & 63;
    int l15 = lane & 15, g = lane >> 4;
    int wm = wave >> 1, wn = wave & 1;

    // staging sources. A chunk c (0..1023): row=c>>3, phys slot sp=c&7 holds
    // logical slot s = sp ^ (row&7)  (16B slots). W chunk c (0..511): linear.
    const float* asrc[4];
    int aoff[4];
#pragma unroll
    for (int i = 0; i < 4; ++i) {
        int c = t + i * 256;
        int row = c >> 3, sp = c & 7, s = sp ^ (row & 7);
        asrc[i] = hid + (size_t)(bt * SS + mt * 128 + row) * HH + s * 4;
        aoff[i] = c * 16;
    }
    const unsigned short* wsrc[2];
    int woff[2];
#pragma unroll
    for (int i = 0; i < 2; ++i) {
        int c = t + i * 256;
        int row = c >> 2, sp = c & 3;
        wsrc[i] = Wt + ((size_t)e << 20) + (size_t)(nt * 128 + row) * HH + sp * 8;
        woff[i] = c * 16;
    }

    auto stage = [&](int ks, int sel) {
#pragma unroll
        for (int i = 0; i < 4; ++i)
            __builtin_amdgcn_global_load_lds(
                (const __attribute__((address_space(1))) void*)(asrc[i] + ks * 32),
                (__attribute__((address_space(3))) void*)(lds + sel * 16384 + aoff[i]),
                16, 0, 0);
#pragma unroll
        for (int i = 0; i < 2; ++i)
            __builtin_amdgcn_global_load_lds(
                (const __attribute__((address_space(1))) void*)(wsrc[i] + ks * 32),
                (__attribute__((address_space(3))) void*)(lds + 32768 + sel * 8192 + woff[i]),
                16, 0, 0);
    };

    f32x4 acc[4][4] = {};

    stage(0, 0);
    __syncthreads();

    for (int ks = 0; ks < 32; ++ks) {
        int sel = ks & 1;
        if (ks < 31) stage(ks + 1, sel ^ 1);

        const char* Af = lds + sel * 16384;
        const char* Wf = lds + 32768 + sel * 8192;

        bhalf8 af[4], bf[4];
#pragma unroll
        for (int mf = 0; mf < 4; ++mf) {
            int row  = wm * 64 + mf * 16 + l15;
            int base = row * 128 + g * 32;
            int sw   = (row & 7) << 4;
            float4 f0 = *(const float4*)(Af + (base ^ sw));
            float4 f1 = *(const float4*)(Af + ((base + 16) ^ sw));
            union { unsigned int u[4]; bhalf8 h; } cv;
            cv.u[0] = pack2(f0.x, f0.y); cv.u[1] = pack2(f0.z, f0.w);
            cv.u[2] = pack2(f1.x, f1.y); cv.u[3] = pack2(f1.z, f1.w);
            af[mf] = cv.h;
        }
#pragma unroll
        for (int nf = 0; nf < 4; ++nf) {
            int row = wn * 64 + nf * 16 + l15;
            bf[nf] = *(const bhalf8*)(Wf + row * 64 + g * 16);
        }
#pragma unroll
        for (int mf = 0; mf < 4; ++mf)
#pragma unroll
            for (int nf = 0; nf < 4; ++nf)
                acc[mf][nf] = __builtin_amdgcn_mfma_f32_16x16x32_bf16(
                    af[mf], bf[nf], acc[mf][nf], 0, 0, 0);
        __syncthreads();
    }

    // ---- epilogue: x = acc + bias + inp; write x to out ----
    int brow = bt * SS + mt * 128;
#pragma unroll
    for (int nf = 0; nf < 4; ++nf) {
        int dcol = nt * 128 + wn * 64 + nf * 16 + l15;
        float bv = bias[e * HH + dcol];
#pragma unroll
        for (int mf = 0; mf < 4; ++mf)
#pragma unroll
            for (int j = 0; j < 4; ++j) {
                int srow = brow + wm * 64 + mf * 16 + g * 4 + j;
                size_t off = (size_t)srow * HH + dcol;
                float v = acc[mf][nf][j] + bv + inp[off];
                acc[mf][nf][j] = v;
                out[off] = v;
            }
    }

    // ---- per-row partial sums (16-lane shuffle reduce) + atomics ----
#pragma unroll
    for (int mf = 0; mf < 4; ++mf)
#pragma unroll
        for (int j = 0; j < 4; ++j) {
            float s1 = 0.f, s2 = 0.f;
#pragma unroll
            for (int nf = 0; nf < 4; ++nf) {
                float v = acc[mf][nf][j];
                s1 += v; s2 += v * v;
            }
#pragma unroll
            for (int m = 8; m >= 1; m >>= 1) {
                s1 += __shfl_xor(s1, m, 64);
                s2 += __shfl_xor(s2, m, 64);
            }
            if (l15 == 0) {
                int r = brow + wm * 64 + mf * 16 + g * 4 + j;
                atomicAdd(&sums[r * 2], s1);
                atomicAdd(&sums[r * 2 + 1], s2);
            }
        }
}

// ---------------------------------------------------------------------------
// LN apply: one block per row; mean/var from precomputed sums; in-place.
// ---------------------------------------------------------------------------
__global__ __launch_bounds__(256)
void ln_apply(float* __restrict__ x, const float* __restrict__ sums,
              const float* __restrict__ gamma, const float* __restrict__ beta)
{
    int row = blockIdx.x;
    int t = threadIdx.x;
    float s1 = sums[row * 2], s2 = sums[row * 2 + 1];
    float mu  = s1 * (1.0f / HH);
    float var = s2 * (1.0f / HH) - mu * mu;
    float rs = rsqrtf(var + 1e-12f);
    size_t base = (size_t)row * HH + t * 4;
    float4 v  = *reinterpret_cast<const float4*>(&x[base]);
    float4 gv = *reinterpret_cast<const float4*>(&gamma[t * 4]);
    float4 bv = *reinterpret_cast<const float4*>(&beta[t * 4]);
    float4 o;
    o.x = (v.x - mu) * rs * gv.x + bv.x;
    o.y = (v.y - mu) * rs * gv.y + bv.y;
    o.z = (v.z - mu) * rs * gv.z + bv.z;
    o.w = (v.w - mu) * rs * gv.w + bv.w;
    *reinterpret_cast<float4*>(&x[base]) = o;
}

extern "C" void kernel_launch(void* const* d_in, const int* in_sizes, int n_in,
                              void* d_out, int out_size, void* d_ws, size_t ws_size,
                              hipStream_t stream) {
    const float* hid   = (const float*)d_in[0];
    const float* inp   = (const float*)d_in[1];
    const int*   eidx  = (const int*)d_in[2];
    const float* W     = (const float*)d_in[3];
    const float* bias  = (const float*)d_in[4];
    const float* gamma = (const float*)d_in[5];
    const float* beta  = (const float*)d_in[6];
    float* out = (float*)d_out;

    unsigned short* Wt = (unsigned short*)d_ws;            // 16 MiB bf16 [8][1024][1024] (d-major)
    float* sums = (float*)((char*)d_ws + (16u << 20));     // 8192 rows x {S1,S2}

    prep_kernel<<<2064, 256, 0, stream>>>(W, eidx, Wt, sums);
    moe_gemm_kernel<<<512, 256, 0, stream>>>(hid, inp, eidx, Wt, bias, sums, out);
    ln_apply<<<BB * SS, 256, 0, stream>>>(out, sums, gamma, beta);
}

// Round 4
// 72.410 us; speedup vs baseline: 1.0276x; 1.0276x over previous
//
#include <hip/hip_runtime.h>
#include <hip/hip_bf16.h>

#define BB 16
#define SS 512
#define HH 1024

typedef __attribute__((ext_vector_type(4))) float f32x4;
typedef __attribute__((ext_vector_type(8))) short bhalf8;

static __device__ __forceinline__ unsigned int pack2(float a, float b) {
    __hip_bfloat162 h = __float22bfloat162_rn(make_float2(a, b));
    union { __hip_bfloat162 h; unsigned int u; } cv;
    cv.h = h;
    return cv.u;
}

// ---------------------------------------------------------------------------
// Prepass: blocks 0..2047: W[e][k][d] f32 -> Wt[e][d][k] bf16 (only for
// experts actually selected); blocks 2048..2063: zero the row-sum buffer.
// ---------------------------------------------------------------------------
__global__ __launch_bounds__(256)
void prep_kernel(const float* __restrict__ W, const int* __restrict__ eidx,
                 unsigned short* __restrict__ Wt, float* __restrict__ sums)
{
    int bid = blockIdx.x;
    int t = threadIdx.x;
    if (bid < 2048) {
        int e  = bid >> 8;
        bool used = false;
        for (int b = 0; b < BB; ++b) used = used || (eidx[b] == e);
        if (!used) return;
        int rem = bid & 255;
        int kt = rem >> 3, dt = rem & 7;     // 32-k-row x 128-d-col tile
        int kb = t & 7, db = t >> 3;
        const float* src = W + ((size_t)e << 20) + (size_t)(kt * 32 + kb * 4) * HH + dt * 128 + db * 4;
        float4 r0 = *(const float4*)(src);
        float4 r1 = *(const float4*)(src + HH);
        float4 r2 = *(const float4*)(src + 2 * HH);
        float4 r3 = *(const float4*)(src + 3 * HH);
        unsigned short* dst = Wt + ((size_t)e << 20) + (size_t)(dt * 128 + db * 4) * HH + kt * 32 + kb * 4;
#pragma unroll
        for (int c = 0; c < 4; ++c) {
            float c0 = (&r0.x)[c], c1 = (&r1.x)[c], c2 = (&r2.x)[c], c3 = (&r3.x)[c];
            *reinterpret_cast<uint2*>(dst + (size_t)c * HH) =
                make_uint2(pack2(c0, c1), pack2(c2, c3));
        }
    } else {
        int i = (bid - 2048) * 1024 + t * 4;   // 16 blocks cover 16384 floats
        float4 z = {0.f, 0.f, 0.f, 0.f};
        *reinterpret_cast<float4*>(&sums[i]) = z;
    }
}

// ---------------------------------------------------------------------------
// GEMM (+bias+residual): 512 blocks x 512 thr (8 waves, 4m x 2n), 128x128
// tile, BK=32, TRIPLE-buffered LDS, counted vmcnt(3) (never drain in-loop),
// global_load_lds width-16, XOR-swizzled A (f32) and W (bf16) tiles,
// mfma 16x16x32 bf16 (8/wave/iter). Writes x to out + per-row {S1,S2} atomics.
// ---------------------------------------------------------------------------
__global__ __launch_bounds__(512, 4)
void moe_gemm_kernel(const float* __restrict__ hid, const float* __restrict__ inp,
                     const int* __restrict__ eidx, const unsigned short* __restrict__ Wt,
                     const float* __restrict__ bias, float* __restrict__ sums,
                     float* __restrict__ out)
{
    __shared__ char ldsA[3 * 16384];   // A: f32 [128 rows][32 k], swizzled 16B slots
    __shared__ char ldsW[3 * 8192];    // W: bf16 [128 d-rows][32 k], swizzled 16B slots

    int bx  = blockIdx.x;
    int swz = (bx & 7) * 64 + (bx >> 3);      // XCD-bijective (512 % 8 == 0)
    int bt   = swz >> 5;
    int tile = swz & 31;
    int mt = tile >> 3, nt = tile & 7;
    int e = eidx[bt];

    int t = threadIdx.x, wave = t >> 6, lane = t & 63;
    int l15 = lane & 15, g = (lane >> 4) & 3;
    int wm = wave >> 1, wn = wave & 1;        // 4 x 2 wave grid: 32-row x 64-col each

    // ---- staging descriptors ----
    // A: 1024 chunks of 16B; chunk c: row=c>>3, phys slot sp=c&7 <- logical s=sp^(row&7)
    const float* asrc[2];
    int aoff[2];
#pragma unroll
    for (int i = 0; i < 2; ++i) {
        int c = t + i * 512;
        int row = c >> 3, sp = c & 7, s = sp ^ (row & 7);
        asrc[i] = hid + (size_t)(bt * SS + mt * 128 + row) * HH + s * 4;
        aoff[i] = c * 16;
    }
    // W: 512 chunks of 16B; chunk c: row=c>>2, phys slot sp=c&3 <- logical s=sp^(row&3)
    int wrow = t >> 2, wsp = t & 3;
    const unsigned short* wsrc = Wt + ((size_t)e << 20)
                               + (size_t)(nt * 128 + wrow) * HH + (wsp ^ (wrow & 3)) * 8;
    int woff = t * 16;

    auto stage = [&](int ks, int p) {
#pragma unroll
        for (int i = 0; i < 2; ++i)
            __builtin_amdgcn_global_load_lds(
                (const __attribute__((address_space(1))) void*)(asrc[i] + ks * 32),
                (__attribute__((address_space(3))) void*)(ldsA + p * 16384 + aoff[i]),
                16, 0, 0);
        __builtin_amdgcn_global_load_lds(
            (const __attribute__((address_space(1))) void*)(wsrc + ks * 32),
            (__attribute__((address_space(3))) void*)(ldsW + p * 8192 + woff),
            16, 0, 0);
    };

    f32x4 acc[2][4] = {};

    stage(0, 0);
    stage(1, 1);

    for (int ks = 0; ks < 32; ++ks) {
        if (ks < 31) { asm volatile("s_waitcnt vmcnt(3)" ::: "memory"); }
        else         { asm volatile("s_waitcnt vmcnt(0)" ::: "memory"); }
        __builtin_amdgcn_s_barrier();
        __builtin_amdgcn_sched_barrier(0);

        if (ks < 30) stage(ks + 2, (ks + 2) % 3);

        const char* Af = ldsA + (ks % 3) * 16384;
        const char* Wf = ldsW + (ks % 3) * 8192;

        bhalf8 af[2], bf[4];
#pragma unroll
        for (int mf = 0; mf < 2; ++mf) {
            int row = wm * 32 + mf * 16 + l15;
            int sl  = row * 8 + g * 2;
            f32x4 f0 = *(const f32x4*)(Af + ((sl ^ (row & 7)) << 4));
            f32x4 f1 = *(const f32x4*)(Af + (((sl + 1) ^ (row & 7)) << 4));
            union { unsigned int u[4]; bhalf8 h; } cv;
            cv.u[0] = pack2(f0[0], f0[1]); cv.u[1] = pack2(f0[2], f0[3]);
            cv.u[2] = pack2(f1[0], f1[1]); cv.u[3] = pack2(f1[2], f1[3]);
            af[mf] = cv.h;
        }
#pragma unroll
        for (int nf = 0; nf < 4; ++nf) {
            int row = wn * 64 + nf * 16 + l15;
            int sl  = row * 4 + (g ^ (row & 3));
            bf[nf] = *(const bhalf8*)(Wf + (sl << 4));
        }
#pragma unroll
        for (int mf = 0; mf < 2; ++mf)
#pragma unroll
            for (int nf = 0; nf < 4; ++nf)
                acc[mf][nf] = __builtin_amdgcn_mfma_f32_16x16x32_bf16(
                    af[mf], bf[nf], acc[mf][nf], 0, 0, 0);
    }

    // ---- epilogue: x = acc + bias + inp; write x to out ----
    int brow = bt * SS + mt * 128;
#pragma unroll
    for (int nf = 0; nf < 4; ++nf) {
        int dcol = nt * 128 + wn * 64 + nf * 16 + l15;
        float bv = bias[e * HH + dcol];
#pragma unroll
        for (int mf = 0; mf < 2; ++mf)
#pragma unroll
            for (int j = 0; j < 4; ++j) {
                int srow = brow + wm * 32 + mf * 16 + g * 4 + j;
                size_t off = (size_t)srow * HH + dcol;
                float v = acc[mf][nf][j] + bv + inp[off];
                acc[mf][nf][j] = v;
                out[off] = v;
            }
    }

    // ---- per-row partial sums (16-lane shuffle reduce) + atomics ----
#pragma unroll
    for (int mf = 0; mf < 2; ++mf)
#pragma unroll
        for (int j = 0; j < 4; ++j) {
            float s1 = 0.f, s2 = 0.f;
#pragma unroll
            for (int nf = 0; nf < 4; ++nf) {
                float v = acc[mf][nf][j];
                s1 += v; s2 += v * v;
            }
#pragma unroll
            for (int m = 8; m >= 1; m >>= 1) {
                s1 += __shfl_xor(s1, m, 64);
                s2 += __shfl_xor(s2, m, 64);
            }
            if (l15 == 0) {
                int r = brow + wm * 32 + mf * 16 + g * 4 + j;
                atomicAdd(&sums[r * 2], s1);
                atomicAdd(&sums[r * 2 + 1], s2);
            }
        }
}

// ---------------------------------------------------------------------------
// LN apply: one block per row; mean/var from precomputed sums; in-place.
// ---------------------------------------------------------------------------
__global__ __launch_bounds__(256)
void ln_apply(float* __restrict__ x, const float* __restrict__ sums,
              const float* __restrict__ gamma, const float* __restrict__ beta)
{
    int row = blockIdx.x;
    int t = threadIdx.x;
    float s1 = sums[row * 2], s2 = sums[row * 2 + 1];
    float mu  = s1 * (1.0f / HH);
    float var = s2 * (1.0f / HH) - mu * mu;
    float rs = rsqrtf(var + 1e-12f);
    size_t base = (size_t)row * HH + t * 4;
    float4 v  = *reinterpret_cast<const float4*>(&x[base]);
    float4 gv = *reinterpret_cast<const float4*>(&gamma[t * 4]);
    float4 bv = *reinterpret_cast<const float4*>(&beta[t * 4]);
    float4 o;
    o.x = (v.x - mu) * rs * gv.x + bv.x;
    o.y = (v.y - mu) * rs * gv.y + bv.y;
    o.z = (v.z - mu) * rs * gv.z + bv.z;
    o.w = (v.w - mu) * rs * gv.w + bv.w;
    *reinterpret_cast<float4*>(&x[base]) = o;
}

extern "C" void kernel_launch(void* const* d_in, const int* in_sizes, int n_in,
                              void* d_out, int out_size, void* d_ws, size_t ws_size,
                              hipStream_t stream) {
    const float* hid   = (const float*)d_in[0];
    const float* inp   = (const float*)d_in[1];
    const int*   eidx  = (const int*)d_in[2];
    const float* W     = (const float*)d_in[3];
    const float* bias  = (const float*)d_in[4];
    const float* gamma = (const float*)d_in[5];
    const float* beta  = (const float*)d_in[6];
    float* out = (float*)d_out;

    unsigned short* Wt = (unsigned short*)d_ws;            // 16 MiB bf16 [8][1024][1024] (d-major)
    float* sums = (float*)((char*)d_ws + (16u << 20));     // 8192 rows x {S1,S2}

    prep_kernel<<<2064, 256, 0, stream>>>(W, eidx, Wt, sums);
    moe_gemm_kernel<<<512, 512, 0, stream>>>(hid, inp, eidx, Wt, bias, sums, out);
    ln_apply<<<BB * SS, 256, 0, stream>>>(out, sums, gamma, beta);
}